// Round 5
// baseline (333.404 us; speedup 1.0000x reference)
//
#include <hip/hip_runtime.h>

typedef unsigned short u16;
typedef short bf16x8 __attribute__((ext_vector_type(8)));
typedef float f32x4 __attribute__((ext_vector_type(4)));

#define D_IN 2048
#define H_DIM 2048
#define K_CH 4096

__device__ __forceinline__ u16 f2bf(float f) {
  unsigned int u = __float_as_uint(f);
  u += 0x7fffu + ((u >> 16) & 1u);   // round-to-nearest-even
  return (u16)(u >> 16);
}
__device__ __forceinline__ float sigmoidf(float x) {
  return 1.0f / (1.0f + __expf(-x));
}
__device__ __forceinline__ uint4 packrow(float4 a, float4 b) {
  uint4 w;
  w.x = (unsigned)f2bf(a.x) | ((unsigned)f2bf(a.y) << 16);
  w.y = (unsigned)f2bf(a.z) | ((unsigned)f2bf(a.w) << 16);
  w.z = (unsigned)f2bf(b.x) | ((unsigned)f2bf(b.y) << 16);
  w.w = (unsigned)f2bf(b.z) | ((unsigned)f2bf(b.w) << 16);
  return w;
}

// ---------------------------------------------------------------------------
// Kernel A (prep, no atomics, 1536 blocks for full-device occupancy):
//  blocks 0..1023:  4 rows of children_h each: column-sum + bf16 convert;
//                   per-block partial sums -> partials[block][2048]
//  blocks 1024..1535: wfhb = bf16(W_fh), 8192 elems/block, 8 loads in flight
// ---------------------------------------------------------------------------
__global__ __launch_bounds__(256) void kprep(const float* __restrict__ ch,
                                             const float* __restrict__ wfh,
                                             float* __restrict__ partials,
                                             u16* __restrict__ chb,
                                             u16* __restrict__ wfhb) {
  const int t = threadIdx.x;
  if (blockIdx.x < 1024) {
    const int r0 = blockIdx.x * 4;
    float4 a[4], b[4];
#pragma unroll
    for (int r = 0; r < 4; ++r) {
      const float4* p = (const float4*)(ch + (size_t)(r0 + r) * H_DIM + t * 8);
      a[r] = p[0];
      b[r] = p[1];
    }
    float s0 = 0.f, s1 = 0.f, s2 = 0.f, s3 = 0.f;
    float s4 = 0.f, s5 = 0.f, s6 = 0.f, s7 = 0.f;
#pragma unroll
    for (int r = 0; r < 4; ++r) {
      s0 += a[r].x; s1 += a[r].y; s2 += a[r].z; s3 += a[r].w;
      s4 += b[r].x; s5 += b[r].y; s6 += b[r].z; s7 += b[r].w;
      *(uint4*)(chb + (size_t)(r0 + r) * H_DIM + t * 8) = packrow(a[r], b[r]);
    }
    float4 lo, hi;
    lo.x = s0; lo.y = s1; lo.z = s2; lo.w = s3;
    hi.x = s4; hi.y = s5; hi.z = s6; hi.w = s7;
    float* pp = partials + (size_t)blockIdx.x * H_DIM + t * 8;
    *(float4*)pp = lo;
    *(float4*)(pp + 4) = hi;
  } else {
    const size_t base = (size_t)(blockIdx.x - 1024) * 8192 + t * 8;
    float4 a[4], b[4];
#pragma unroll
    for (int j = 0; j < 4; ++j) {
      const float4* p = (const float4*)(wfh + base + j * 2048);
      a[j] = p[0];
      b[j] = p[1];
    }
#pragma unroll
    for (int j = 0; j < 4; ++j)
      *(uint4*)(wfhb + base + j * 2048) = packrow(a[j], b[j]);
  }
}

// ---------------------------------------------------------------------------
// Kernel A2: hsum[c] = sum_p partials[p][c].  8 blocks x 256 threads; thread
// = column; 8 independent accumulators; fully coalesced across lanes.
// ---------------------------------------------------------------------------
__global__ __launch_bounds__(256) void kred(const float* __restrict__ partials,
                                            float* __restrict__ hsum) {
  const int c = blockIdx.x * 256 + threadIdx.x;
  float a0 = 0.f, a1 = 0.f, a2 = 0.f, a3 = 0.f;
  float a4 = 0.f, a5 = 0.f, a6 = 0.f, a7 = 0.f;
  for (int p = 0; p < 1024; p += 8) {
    a0 += partials[(size_t)(p + 0) * H_DIM + c];
    a1 += partials[(size_t)(p + 1) * H_DIM + c];
    a2 += partials[(size_t)(p + 2) * H_DIM + c];
    a3 += partials[(size_t)(p + 3) * H_DIM + c];
    a4 += partials[(size_t)(p + 4) * H_DIM + c];
    a5 += partials[(size_t)(p + 5) * H_DIM + c];
    a6 += partials[(size_t)(p + 6) * H_DIM + c];
    a7 += partials[(size_t)(p + 7) * H_DIM + c];
  }
  hsum[c] = ((a0 + a1) + (a2 + a3)) + ((a4 + a5) + (a6 + a7));
}

// ---------------------------------------------------------------------------
// Kernel B: one wave per output row, fp32 (unchanged).
// ---------------------------------------------------------------------------
__global__ __launch_bounds__(256) void kmatvec(
    const float* __restrict__ Wix, const float* __restrict__ bix,
    const float* __restrict__ Wih, const float* __restrict__ bih,
    const float* __restrict__ Wfx, const float* __restrict__ bfx,
    const float* __restrict__ bfh, const float* __restrict__ x,
    const float* __restrict__ hsum, float* __restrict__ iou,
    float* __restrict__ g) {
  const int wave = threadIdx.x >> 6, lane = threadIdx.x & 63;
  const int row = blockIdx.x * 4 + wave;  // 0..8191
  float s = 0.f;
  if (row < 6144) {
    const float4* wx = (const float4*)(Wix + (size_t)row * D_IN);
    const float4* wh = (const float4*)(Wih + (size_t)row * H_DIM);
    const float4* xv = (const float4*)x;
    const float4* hv = (const float4*)hsum;
#pragma unroll
    for (int i = 0; i < 8; ++i) {
      int idx = i * 64 + lane;
      float4 a = wx[idx], b = xv[idx];
      s += a.x * b.x + a.y * b.y + a.z * b.z + a.w * b.w;
      float4 c = wh[idx], d = hv[idx];
      s += c.x * d.x + c.y * d.y + c.z * d.z + c.w * d.w;
    }
#pragma unroll
    for (int off = 32; off > 0; off >>= 1) s += __shfl_xor(s, off);
    if (lane == 0) iou[row] = s + bix[row] + bih[row];
  } else {
    const int h = row - 6144;
    const float4* w = (const float4*)(Wfx + (size_t)h * D_IN);
    const float4* xv = (const float4*)x;
#pragma unroll
    for (int i = 0; i < 8; ++i) {
      int idx = i * 64 + lane;
      float4 a = w[idx], b = xv[idx];
      s += a.x * b.x + a.y * b.y + a.z * b.z + a.w * b.w;
    }
#pragma unroll
    for (int off = 32; off > 0; off >>= 1) s += __shfl_xor(s, off);
    if (lane == 0) g[h] = s + bfx[h] + bfh[h];
  }
}

// ---------------------------------------------------------------------------
// Kernel C v2: fused bf16 GEMM + sigmoid + weighted K-reduction.
// 128x128 tile, BK=64 (32 KB LDS, 32 MFMA per barrier), XOR chunk swizzle:
// row r's 16B chunk j lives at LDS slot j^(r&7)  ->  fragment ds_read_b128
// spreads 16 lanes over 8 bank groups (2-way = free) instead of 8-way.
// Swizzle applied at the *global source address* (global_load_lds LDS dest
// is fixed wave-uniform base + lane*16, but source is per-lane).
// ---------------------------------------------------------------------------
#define BM 128
#define BN 128
#define BK 64

__global__ __launch_bounds__(256) void kgemm(
    const u16* __restrict__ chb, const float* __restrict__ cc,
    const u16* __restrict__ wfhb, const float* __restrict__ g,
    float* __restrict__ accv) {
  __shared__ u16 As[BM * BK];  // row stride 64 u16 (128 B), 8 chunks of 16 B
  __shared__ u16 Bs[BN * BK];

  const int t = threadIdx.x;
  const int wave = t >> 6, lane = t & 63;
  const int lrow = lane & 15, lquad = lane >> 4;
  const int wm = wave >> 1, wn = wave & 1;
  const int row0 = blockIdx.x * BM;  // children tile base (32 tiles)
  const int col0 = blockIdx.y * BN;  // h tile base (16 tiles)

  f32x4 acc[4][4] = {};

  // Staging lane map: one global_load_lds covers 8 rows (64 lanes x 16 B).
  const int srow = lane >> 3;           // row within the 8-row group
  const int schunk = (lane & 7) ^ srow; // XOR-swizzled source chunk
  const u16* agbase = chb  + (size_t)(row0 + wave * 32 + srow) * H_DIM + schunk * 8;
  const u16* bgbase = wfhb + (size_t)(col0 + wave * 32 + srow) * H_DIM + schunk * 8;

  for (int kb = 0; kb < D_IN / BK; ++kb) {
    __syncthreads();
#pragma unroll
    for (int i = 0; i < 4; ++i)
      __builtin_amdgcn_global_load_lds(
          (const __attribute__((address_space(1))) void*)(agbase + (size_t)i * 8 * H_DIM + kb * BK),
          (__attribute__((address_space(3))) void*)(As + (wave * 32 + i * 8) * 64),
          16, 0, 0);
#pragma unroll
    for (int i = 0; i < 4; ++i)
      __builtin_amdgcn_global_load_lds(
          (const __attribute__((address_space(1))) void*)(bgbase + (size_t)i * 8 * H_DIM + kb * BK),
          (__attribute__((address_space(3))) void*)(Bs + (wave * 32 + i * 8) * 64),
          16, 0, 0);
    __syncthreads();

#pragma unroll
    for (int step = 0; step < 2; ++step) {
      const int slot = ((step * 4 + lquad) ^ (lrow & 7)) * 8;
      bf16x8 fa[4], fb[4];
#pragma unroll
      for (int i = 0; i < 4; ++i)
        fa[i] = *(const bf16x8*)(As + (wm * 64 + i * 16 + lrow) * 64 + slot);
#pragma unroll
      for (int i = 0; i < 4; ++i)
        fb[i] = *(const bf16x8*)(Bs + (wn * 64 + i * 16 + lrow) * 64 + slot);
#pragma unroll
      for (int mi = 0; mi < 4; ++mi)
#pragma unroll
        for (int ni = 0; ni < 4; ++ni)
          acc[mi][ni] = __builtin_amdgcn_mfma_f32_16x16x32_bf16(
              fa[mi], fb[ni], acc[mi][ni], 0, 0, 0);
    }
  }

  // Epilogue. C/D layout: col = lane&15, row = (lane>>4)*4 + reg.
#pragma unroll
  for (int ni = 0; ni < 4; ++ni) {
    const int colg = col0 + wn * 64 + ni * 16 + lrow;
    const float gv = g[colg];
    float s = 0.f;
#pragma unroll
    for (int mi = 0; mi < 4; ++mi) {
      const int rowg = row0 + wm * 64 + mi * 16 + lquad * 4;
#pragma unroll
      for (int r = 0; r < 4; ++r) {
        float f = sigmoidf(gv + acc[mi][ni][r]);
        s += f * cc[(size_t)(rowg + r) * H_DIM + colg];
      }
    }
    s += __shfl_xor(s, 16);
    s += __shfl_xor(s, 32);
    if (lquad == 0) atomicAdd(accv + colg, s);
  }
}

// ---------------------------------------------------------------------------
// Kernel D: finalize (fp32 out).
// ---------------------------------------------------------------------------
__global__ __launch_bounds__(256) void kfinal(const float* __restrict__ iou,
                                              const float* __restrict__ accv,
                                              float* __restrict__ out) {
  const int h = blockIdx.x * 256 + threadIdx.x;
  float si = sigmoidf(iou[h]);
  float so = sigmoidf(iou[H_DIM + h]);
  float tu = tanhf(iou[2 * H_DIM + h]);
  float c = si * tu + accv[h];
  float hh = so * tanhf(c);
  out[h] = so;
  out[H_DIM + h] = c;
  out[2 * H_DIM + h] = hh;
}

extern "C" void kernel_launch(void* const* d_in, const int* in_sizes, int n_in,
                              void* d_out, int out_size, void* d_ws, size_t ws_size,
                              hipStream_t stream) {
  const float* x   = (const float*)d_in[0];   // input [2048]
  const float* cc  = (const float*)d_in[1];   // children_c [4096,2048]
  const float* ch  = (const float*)d_in[2];   // children_h [4096,2048]
  const float* Wix = (const float*)d_in[3];   // W_iou_x [6144,2048]
  const float* bix = (const float*)d_in[4];   // b_iou_x [6144]
  const float* Wih = (const float*)d_in[5];   // W_iou_h [6144,2048]
  const float* bih = (const float*)d_in[6];   // b_iou_h [6144]
  const float* Wfx = (const float*)d_in[7];   // W_fx [2048,2048]
  const float* bfx = (const float*)d_in[8];   // b_fx [2048]
  const float* Wfh = (const float*)d_in[9];   // W_fh [2048,2048]
  const float* bfh = (const float*)d_in[10];  // b_fh [2048]

  float* ws   = (float*)d_ws;
  float* hsum = ws;                    // [2048]
  float* iou  = ws + 2048;             // [6144]
  float* g    = ws + 8192;             // [2048]
  float* accv = ws + 10240;            // [2048]
  float* partials = ws + 12288;        // [1024 * 2048]
  u16* chb  = (u16*)(ws + 12288 + 1024 * 2048);  // [4096*2048] bf16
  u16* wfhb = chb + (size_t)K_CH * H_DIM;        // [2048*2048] bf16
  float* out = (float*)d_out;

  hipMemsetAsync(accv, 0, 2048 * sizeof(float), stream);
  kprep<<<1536, 256, 0, stream>>>(ch, Wfh, partials, chb, wfhb);
  kred<<<8, 256, 0, stream>>>(partials, hsum);
  kmatvec<<<2048, 256, 0, stream>>>(Wix, bix, Wih, bih, Wfx, bfx, bfh, x, hsum, iou, g);
  kgemm<<<dim3(32, 16), 256, 0, stream>>>(chb, cc, wfhb, g, accv);
  kfinal<<<8, 256, 0, stream>>>(iou, accv, out);
}

// Round 6
// 281.740 us; speedup vs baseline: 1.1834x; 1.1834x over previous
//
#include <hip/hip_runtime.h>

typedef unsigned short u16;
typedef short bf16x8 __attribute__((ext_vector_type(8)));
typedef float f32x4 __attribute__((ext_vector_type(4)));

#define D_IN 2048
#define H_DIM 2048
#define K_CH 4096

__device__ __forceinline__ u16 f2bf(float f) {
  unsigned int u = __float_as_uint(f);
  u += 0x7fffu + ((u >> 16) & 1u);   // round-to-nearest-even
  return (u16)(u >> 16);
}
__device__ __forceinline__ float sigmoidf(float x) {
  return 1.0f / (1.0f + __expf(-x));
}
__device__ __forceinline__ uint4 packrow(float4 a, float4 b) {
  uint4 w;
  w.x = (unsigned)f2bf(a.x) | ((unsigned)f2bf(a.y) << 16);
  w.y = (unsigned)f2bf(a.z) | ((unsigned)f2bf(a.w) << 16);
  w.z = (unsigned)f2bf(b.x) | ((unsigned)f2bf(b.y) << 16);
  w.w = (unsigned)f2bf(b.z) | ((unsigned)f2bf(b.w) << 16);
  return w;
}

// ---------------------------------------------------------------------------
// Kernel A (prep, no atomics, 1536 blocks):
//  blocks 0..1023:  4 rows of children_h: column-sum + bf16 convert;
//                   partial sums -> partials[block][2048]
//  blocks 1024..1535: wfhb = bf16(W_fh), 8192 elems/block
// ---------------------------------------------------------------------------
__global__ __launch_bounds__(256) void kprep(const float* __restrict__ ch,
                                             const float* __restrict__ wfh,
                                             float* __restrict__ partials,
                                             u16* __restrict__ chb,
                                             u16* __restrict__ wfhb) {
  const int t = threadIdx.x;
  if (blockIdx.x < 1024) {
    const int r0 = blockIdx.x * 4;
    float4 a[4], b[4];
#pragma unroll
    for (int r = 0; r < 4; ++r) {
      const float4* p = (const float4*)(ch + (size_t)(r0 + r) * H_DIM + t * 8);
      a[r] = p[0];
      b[r] = p[1];
    }
    float s0 = 0.f, s1 = 0.f, s2 = 0.f, s3 = 0.f;
    float s4 = 0.f, s5 = 0.f, s6 = 0.f, s7 = 0.f;
#pragma unroll
    for (int r = 0; r < 4; ++r) {
      s0 += a[r].x; s1 += a[r].y; s2 += a[r].z; s3 += a[r].w;
      s4 += b[r].x; s5 += b[r].y; s6 += b[r].z; s7 += b[r].w;
      *(uint4*)(chb + (size_t)(r0 + r) * H_DIM + t * 8) = packrow(a[r], b[r]);
    }
    float4 lo, hi;
    lo.x = s0; lo.y = s1; lo.z = s2; lo.w = s3;
    hi.x = s4; hi.y = s5; hi.z = s6; hi.w = s7;
    float* pp = partials + (size_t)blockIdx.x * H_DIM + t * 8;
    *(float4*)pp = lo;
    *(float4*)(pp + 4) = hi;
  } else {
    const size_t base = (size_t)(blockIdx.x - 1024) * 8192 + t * 8;
    float4 a[4], b[4];
#pragma unroll
    for (int j = 0; j < 4; ++j) {
      const float4* p = (const float4*)(wfh + base + j * 2048);
      a[j] = p[0];
      b[j] = p[1];
    }
#pragma unroll
    for (int j = 0; j < 4; ++j)
      *(uint4*)(wfhb + base + j * 2048) = packrow(a[j], b[j]);
  }
}

// ---------------------------------------------------------------------------
// Kernel A2 v2: hsum[c] += partial sums.  Grid (8 col-groups, 8 p-groups) =
// 64 blocks = 256 waves; each thread sums 128 partials (8 chains) and does
// ONE atomicAdd (16K atomics total, 8 per address ~= 2 us at measured rate).
// ---------------------------------------------------------------------------
__global__ __launch_bounds__(256) void kred(const float* __restrict__ partials,
                                            float* __restrict__ hsum) {
  const int c = blockIdx.x * 256 + threadIdx.x;
  const int p0 = blockIdx.y * 128;
  float a0 = 0.f, a1 = 0.f, a2 = 0.f, a3 = 0.f;
  float a4 = 0.f, a5 = 0.f, a6 = 0.f, a7 = 0.f;
  for (int p = p0; p < p0 + 128; p += 8) {
    a0 += partials[(size_t)(p + 0) * H_DIM + c];
    a1 += partials[(size_t)(p + 1) * H_DIM + c];
    a2 += partials[(size_t)(p + 2) * H_DIM + c];
    a3 += partials[(size_t)(p + 3) * H_DIM + c];
    a4 += partials[(size_t)(p + 4) * H_DIM + c];
    a5 += partials[(size_t)(p + 5) * H_DIM + c];
    a6 += partials[(size_t)(p + 6) * H_DIM + c];
    a7 += partials[(size_t)(p + 7) * H_DIM + c];
  }
  float s = ((a0 + a1) + (a2 + a3)) + ((a4 + a5) + (a6 + a7));
  atomicAdd(hsum + c, s);
}

// ---------------------------------------------------------------------------
// Kernel B: one wave per output row, fp32 (unchanged).
// ---------------------------------------------------------------------------
__global__ __launch_bounds__(256) void kmatvec(
    const float* __restrict__ Wix, const float* __restrict__ bix,
    const float* __restrict__ Wih, const float* __restrict__ bih,
    const float* __restrict__ Wfx, const float* __restrict__ bfx,
    const float* __restrict__ bfh, const float* __restrict__ x,
    const float* __restrict__ hsum, float* __restrict__ iou,
    float* __restrict__ g) {
  const int wave = threadIdx.x >> 6, lane = threadIdx.x & 63;
  const int row = blockIdx.x * 4 + wave;  // 0..8191
  float s = 0.f;
  if (row < 6144) {
    const float4* wx = (const float4*)(Wix + (size_t)row * D_IN);
    const float4* wh = (const float4*)(Wih + (size_t)row * H_DIM);
    const float4* xv = (const float4*)x;
    const float4* hv = (const float4*)hsum;
#pragma unroll
    for (int i = 0; i < 8; ++i) {
      int idx = i * 64 + lane;
      float4 a = wx[idx], b = xv[idx];
      s += a.x * b.x + a.y * b.y + a.z * b.z + a.w * b.w;
      float4 c = wh[idx], d = hv[idx];
      s += c.x * d.x + c.y * d.y + c.z * d.z + c.w * d.w;
    }
#pragma unroll
    for (int off = 32; off > 0; off >>= 1) s += __shfl_xor(s, off);
    if (lane == 0) iou[row] = s + bix[row] + bih[row];
  } else {
    const int h = row - 6144;
    const float4* w = (const float4*)(Wfx + (size_t)h * D_IN);
    const float4* xv = (const float4*)x;
#pragma unroll
    for (int i = 0; i < 8; ++i) {
      int idx = i * 64 + lane;
      float4 a = w[idx], b = xv[idx];
      s += a.x * b.x + a.y * b.y + a.z * b.z + a.w * b.w;
    }
#pragma unroll
    for (int off = 32; off > 0; off >>= 1) s += __shfl_xor(s, off);
    if (lane == 0) g[h] = s + bfx[h] + bfh[h];
  }
}

// ---------------------------------------------------------------------------
// Kernel C v2 (unchanged from round 5): fused bf16 GEMM + sigmoid + weighted
// K-reduction. 128x128 tile, BK=64, XOR chunk swizzle on LDS layout.
// ---------------------------------------------------------------------------
#define BM 128
#define BN 128
#define BK 64

__global__ __launch_bounds__(256) void kgemm(
    const u16* __restrict__ chb, const float* __restrict__ cc,
    const u16* __restrict__ wfhb, const float* __restrict__ g,
    float* __restrict__ accv) {
  __shared__ u16 As[BM * BK];  // row stride 64 u16 (128 B), 8 chunks of 16 B
  __shared__ u16 Bs[BN * BK];

  const int t = threadIdx.x;
  const int wave = t >> 6, lane = t & 63;
  const int lrow = lane & 15, lquad = lane >> 4;
  const int wm = wave >> 1, wn = wave & 1;
  const int row0 = blockIdx.x * BM;
  const int col0 = blockIdx.y * BN;

  f32x4 acc[4][4] = {};

  const int srow = lane >> 3;           // row within the 8-row group
  const int schunk = (lane & 7) ^ srow; // XOR-swizzled source chunk
  const u16* agbase = chb  + (size_t)(row0 + wave * 32 + srow) * H_DIM + schunk * 8;
  const u16* bgbase = wfhb + (size_t)(col0 + wave * 32 + srow) * H_DIM + schunk * 8;

  for (int kb = 0; kb < D_IN / BK; ++kb) {
    __syncthreads();
#pragma unroll
    for (int i = 0; i < 4; ++i)
      __builtin_amdgcn_global_load_lds(
          (const __attribute__((address_space(1))) void*)(agbase + (size_t)i * 8 * H_DIM + kb * BK),
          (__attribute__((address_space(3))) void*)(As + (wave * 32 + i * 8) * 64),
          16, 0, 0);
#pragma unroll
    for (int i = 0; i < 4; ++i)
      __builtin_amdgcn_global_load_lds(
          (const __attribute__((address_space(1))) void*)(bgbase + (size_t)i * 8 * H_DIM + kb * BK),
          (__attribute__((address_space(3))) void*)(Bs + (wave * 32 + i * 8) * 64),
          16, 0, 0);
    __syncthreads();

#pragma unroll
    for (int step = 0; step < 2; ++step) {
      const int slot = ((step * 4 + lquad) ^ (lrow & 7)) * 8;
      bf16x8 fa[4], fb[4];
#pragma unroll
      for (int i = 0; i < 4; ++i)
        fa[i] = *(const bf16x8*)(As + (wm * 64 + i * 16 + lrow) * 64 + slot);
#pragma unroll
      for (int i = 0; i < 4; ++i)
        fb[i] = *(const bf16x8*)(Bs + (wn * 64 + i * 16 + lrow) * 64 + slot);
#pragma unroll
      for (int mi = 0; mi < 4; ++mi)
#pragma unroll
        for (int ni = 0; ni < 4; ++ni)
          acc[mi][ni] = __builtin_amdgcn_mfma_f32_16x16x32_bf16(
              fa[mi], fb[ni], acc[mi][ni], 0, 0, 0);
    }
  }

  // Epilogue. C/D layout: col = lane&15, row = (lane>>4)*4 + reg.
#pragma unroll
  for (int ni = 0; ni < 4; ++ni) {
    const int colg = col0 + wn * 64 + ni * 16 + lrow;
    const float gv = g[colg];
    float s = 0.f;
#pragma unroll
    for (int mi = 0; mi < 4; ++mi) {
      const int rowg = row0 + wm * 64 + mi * 16 + lquad * 4;
#pragma unroll
      for (int r = 0; r < 4; ++r) {
        float f = sigmoidf(gv + acc[mi][ni][r]);
        s += f * cc[(size_t)(rowg + r) * H_DIM + colg];
      }
    }
    s += __shfl_xor(s, 16);
    s += __shfl_xor(s, 32);
    if (lquad == 0) atomicAdd(accv + colg, s);
  }
}

// ---------------------------------------------------------------------------
// Kernel D: finalize (fp32 out).
// ---------------------------------------------------------------------------
__global__ __launch_bounds__(256) void kfinal(const float* __restrict__ iou,
                                              const float* __restrict__ accv,
                                              float* __restrict__ out) {
  const int h = blockIdx.x * 256 + threadIdx.x;
  float si = sigmoidf(iou[h]);
  float so = sigmoidf(iou[H_DIM + h]);
  float tu = tanhf(iou[2 * H_DIM + h]);
  float c = si * tu + accv[h];
  float hh = so * tanhf(c);
  out[h] = so;
  out[H_DIM + h] = c;
  out[2 * H_DIM + h] = hh;
}

extern "C" void kernel_launch(void* const* d_in, const int* in_sizes, int n_in,
                              void* d_out, int out_size, void* d_ws, size_t ws_size,
                              hipStream_t stream) {
  const float* x   = (const float*)d_in[0];   // input [2048]
  const float* cc  = (const float*)d_in[1];   // children_c [4096,2048]
  const float* ch  = (const float*)d_in[2];   // children_h [4096,2048]
  const float* Wix = (const float*)d_in[3];   // W_iou_x [6144,2048]
  const float* bix = (const float*)d_in[4];   // b_iou_x [6144]
  const float* Wih = (const float*)d_in[5];   // W_iou_h [6144,2048]
  const float* bih = (const float*)d_in[6];   // b_iou_h [6144]
  const float* Wfx = (const float*)d_in[7];   // W_fx [2048,2048]
  const float* bfx = (const float*)d_in[8];   // b_fx [2048]
  const float* Wfh = (const float*)d_in[9];   // W_fh [2048,2048]
  const float* bfh = (const float*)d_in[10];  // b_fh [2048]

  float* ws   = (float*)d_ws;
  float* hsum = ws;                    // [2048]  (zeroed; kred atomics)
  float* iou  = ws + 2048;             // [6144]
  float* g    = ws + 8192;             // [2048]
  float* accv = ws + 10240;            // [2048]  (zeroed; kgemm atomics)
  float* partials = ws + 12288;        // [1024 * 2048]
  u16* chb  = (u16*)(ws + 12288 + 1024 * 2048);  // [4096*2048] bf16
  u16* wfhb = chb + (size_t)K_CH * H_DIM;        // [2048*2048] bf16
  float* out = (float*)d_out;

  hipMemsetAsync(ws, 0, 12288 * sizeof(float), stream);
  kprep<<<1536, 256, 0, stream>>>(ch, Wfh, partials, chb, wfhb);
  kred<<<dim3(8, 8), 256, 0, stream>>>(partials, hsum);
  kmatvec<<<2048, 256, 0, stream>>>(Wix, bix, Wih, bih, Wfx, bfx, bfh, x, hsum, iou, g);
  kgemm<<<dim3(32, 16), 256, 0, stream>>>(chb, cc, wfhb, g, accv);
  kfinal<<<8, 256, 0, stream>>>(iou, accv, out);
}